// Round 1
// baseline (5303.651 us; speedup 1.0000x reference)
//
#include <hip/hip_runtime.h>
#include <hip/hip_bf16.h>

#define HDIM 32

__device__ __forceinline__ float sigm(float x) {
    return __fdividef(1.0f, 1.0f + __expf(-x));
}
__device__ __forceinline__ float tanh_fast(float x) {
    // tanh(x) = 1 - 2/(exp(2x)+1); saturates correctly via inf/rcp semantics
    return 1.0f - __fdividef(2.0f, 1.0f + __expf(2.0f * x));
}

// One LSTM cell step. DIN inputs in x[], state h[32]/c[32], new hidden -> hn[32].
// Weight/bias indices are loop-constant + pointers uniform => scalar (s_load) path.
template<int DIN>
__device__ __forceinline__ void lstm_step(
    const float* __restrict__ Wih, const float* __restrict__ Whh,
    const float* __restrict__ bias,
    const float* x, const float* h, float* c, float* hn)
{
#pragma unroll
    for (int j = 0; j < HDIM; ++j) {
        float gi = bias[j];
        float gf = bias[HDIM + j];
        float gg = bias[2 * HDIM + j];
        float go = bias[3 * HDIM + j];
#pragma unroll
        for (int d = 0; d < DIN; ++d) {
            float xv = x[d];
            gi += Wih[(j           ) * DIN + d] * xv;
            gf += Wih[(HDIM + j    ) * DIN + d] * xv;
            gg += Wih[(2 * HDIM + j) * DIN + d] * xv;
            go += Wih[(3 * HDIM + j) * DIN + d] * xv;
        }
#pragma unroll
        for (int k = 0; k < HDIM; ++k) {
            float hv = h[k];
            gi += Whh[(j           ) * HDIM + k] * hv;
            gf += Whh[(HDIM + j    ) * HDIM + k] * hv;
            gg += Whh[(2 * HDIM + j) * HDIM + k] * hv;
            go += Whh[(3 * HDIM + j) * HDIM + k] * hv;
        }
        float cv = sigm(gf) * c[j] + sigm(gi) * tanh_fast(gg);
        c[j] = cv;
        hn[j] = sigm(go) * tanh_fast(cv);
    }
}

// Layer-1 step with split 64-wide input (xa = fwd L0 hidden, xb = bwd L0 hidden)
__device__ __forceinline__ void lstm_step_l1(
    const float* __restrict__ Wih, const float* __restrict__ Whh,
    const float* __restrict__ bias,
    const float* xa, const float* xb, const float* h, float* c, float* hn)
{
#pragma unroll
    for (int j = 0; j < HDIM; ++j) {
        float gi = bias[j];
        float gf = bias[HDIM + j];
        float gg = bias[2 * HDIM + j];
        float go = bias[3 * HDIM + j];
#pragma unroll
        for (int k = 0; k < HDIM; ++k) {
            float xv = xa[k];
            gi += Wih[(j           ) * 64 + k] * xv;
            gf += Wih[(HDIM + j    ) * 64 + k] * xv;
            gg += Wih[(2 * HDIM + j) * 64 + k] * xv;
            go += Wih[(3 * HDIM + j) * 64 + k] * xv;
        }
#pragma unroll
        for (int k = 0; k < HDIM; ++k) {
            float xv = xb[k];
            gi += Wih[(j           ) * 64 + HDIM + k] * xv;
            gf += Wih[(HDIM + j    ) * 64 + HDIM + k] * xv;
            gg += Wih[(2 * HDIM + j) * 64 + HDIM + k] * xv;
            go += Wih[(3 * HDIM + j) * 64 + HDIM + k] * xv;
        }
#pragma unroll
        for (int k = 0; k < HDIM; ++k) {
            float hv = h[k];
            gi += Whh[(j           ) * HDIM + k] * hv;
            gf += Whh[(HDIM + j    ) * HDIM + k] * hv;
            gg += Whh[(2 * HDIM + j) * HDIM + k] * hv;
            go += Whh[(3 * HDIM + j) * HDIM + k] * hv;
        }
        float cv = sigm(gf) * c[j] + sigm(gi) * tanh_fast(gg);
        c[j] = cv;
        hn[j] = sigm(go) * tanh_fast(cv);
    }
}

// One thread = one (model, half, sample). Fully fused 2-layer biLSTM + FC.
__global__ __launch_bounds__(256, 2) void lstm_fused(
    const float* __restrict__ dir_input,   // [32768,6]
    const float* __restrict__ pos,         // [32768,30,4]
    const float* __restrict__ lvl_Wih0, const float* __restrict__ lvl_Whh0,
    const float* __restrict__ lvl_b0,
    const float* __restrict__ lvl_Wih1, const float* __restrict__ lvl_Whh1,
    const float* __restrict__ lvl_b1,
    const float* __restrict__ vor_Wih0, const float* __restrict__ vor_Whh0,
    const float* __restrict__ vor_b0,
    const float* __restrict__ vor_Wih1, const float* __restrict__ vor_Whh1,
    const float* __restrict__ vor_b1,
    const float* __restrict__ lvl_fc_W, const float* __restrict__ lvl_fc_b,
    const float* __restrict__ vor_fc_W, const float* __restrict__ vor_fc_b,
    float* __restrict__ out)               // [32768,2], pre-zeroed
{
    const int m    = blockIdx.y;                       // 0 = lvl, 1 = vor (block-uniform)
    const int s    = blockIdx.x * 256 + threadIdx.x;   // 0..65535
    const int half = s >> 15;                          // 0 = left, 1 = right
    const int b    = s & 32767;

    const float* Wih0 = m ? vor_Wih0 : lvl_Wih0;   // [2,128,4]
    const float* Whh0 = m ? vor_Whh0 : lvl_Whh0;   // [2,128,32]
    const float* B0   = m ? vor_b0   : lvl_b0;     // [2,128]
    const float* Wih1 = m ? vor_Wih1 : lvl_Wih1;   // [2,128,64]
    const float* Whh1 = m ? vor_Whh1 : lvl_Whh1;   // [2,128,32]
    const float* B1   = m ? vor_b1   : lvl_b1;     // [2,128]

    const float* xbase = pos + ((size_t)b * 30 + half * 15) * 4;

    // L0 backward hidden history -> per-thread private scratch (dynamic t index)
    float hb_st[15 * 32];

    // ---------- Layer 0, backward direction (t = 14 .. 0) ----------
    {
        float h[HDIM], c[HDIM], hn[HDIM];
#pragma unroll
        for (int j = 0; j < HDIM; ++j) { h[j] = 0.0f; c[j] = 0.0f; }
#pragma unroll 1
        for (int t = 14; t >= 0; --t) {
            float x[4];
            const float* xp = xbase + t * 4;
#pragma unroll
            for (int d = 0; d < 4; ++d) x[d] = xp[d];
            lstm_step<4>(Wih0 + 128 * 4, Whh0 + 128 * 32, B0 + 128, x, h, c, hn);
#pragma unroll
            for (int j = 0; j < HDIM; ++j) {
                h[j] = hn[j];
                hb_st[t * 32 + j] = hn[j];
            }
        }
    }

    // ---------- Layer 0 forward + Layer 1 forward, fused scan (t = 0 .. 14) ----------
    float h0[HDIM], c0[HDIM], h1[HDIM], c1[HDIM], hbf[HDIM];
#pragma unroll
    for (int j = 0; j < HDIM; ++j) { h0[j] = 0.0f; c0[j] = 0.0f; h1[j] = 0.0f; c1[j] = 0.0f; }

#pragma unroll 1
    for (int t = 0; t < 15; ++t) {
        float x[4];
        const float* xp = xbase + t * 4;
#pragma unroll
        for (int d = 0; d < 4; ++d) x[d] = xp[d];

        float hn[HDIM];
        lstm_step<4>(Wih0, Whh0, B0, x, h0, c0, hn);
#pragma unroll
        for (int j = 0; j < HDIM; ++j) h0[j] = hn[j];

#pragma unroll
        for (int j = 0; j < HDIM; ++j) hbf[j] = hb_st[t * 32 + j];

        float h1n[HDIM];
        lstm_step_l1(Wih1, Whh1, B1, h0, hbf, h1, c1, h1n);
#pragma unroll
        for (int j = 0; j < HDIM; ++j) h1[j] = h1n[j];
    }
    // Now: h0 = L0 fwd h at t=14, hbf = L0 bwd h at t=14, h1 = L1 fwd h at t=14.

    // ---------- Layer 1 backward, single step from zero state ----------
    // c_prev = 0 => forget-gate term drops; only i, g, o gates needed.
    float h1b[HDIM];
    {
        const float* Wb = Wih1 + 128 * 64;   // dir 1
        const float* bb = B1 + 128;
#pragma unroll
        for (int j = 0; j < HDIM; ++j) {
            float gi = bb[j];
            float gg = bb[2 * HDIM + j];
            float go = bb[3 * HDIM + j];
#pragma unroll
            for (int k = 0; k < HDIM; ++k) {
                float xa = h0[k];
                float xb = hbf[k];
                gi += Wb[(j           ) * 64 + k] * xa + Wb[(j           ) * 64 + HDIM + k] * xb;
                gg += Wb[(2 * HDIM + j) * 64 + k] * xa + Wb[(2 * HDIM + j) * 64 + HDIM + k] * xb;
                go += Wb[(3 * HDIM + j) * 64 + k] * xa + Wb[(3 * HDIM + j) * 64 + HDIM + k] * xb;
            }
            float cv = sigm(gi) * tanh_fast(gg);
            h1b[j] = sigm(go) * tanh_fast(cv);
        }
    }

    // ---------- Masks + FC + atomic combine ----------
    const float* dp = dir_input + (size_t)b * 6;
    float mx = dp[0];
    int dmax = 0;
#pragma unroll
    for (int i = 1; i < 6; ++i) {
        float v = dp[i];
        if (v > mx) { mx = v; dmax = i; }
    }

    float o0, o1;
    if (m == 0) {
        // lvl branch: left half -> mask_l (dirs 2,3); right half -> mask_r (dirs 0,5)
        float mask = (half == 0) ? ((dmax == 2 || dmax == 3) ? 1.0f : 0.0f)
                                 : ((dmax == 0 || dmax == 5) ? 1.0f : 0.0f);
        float a0 = lvl_fc_b[0];
        float a1 = lvl_fc_b[1];
#pragma unroll
        for (int k = 0; k < HDIM; ++k) {
            a0 += lvl_fc_W[k] * h1[k]      + lvl_fc_W[HDIM + k] * h1b[k];
            a1 += lvl_fc_W[64 + k] * h1[k] + lvl_fc_W[64 + HDIM + k] * h1b[k];
        }
        o0 = a0 * mask;
        o1 = a1 * mask;
    } else {
        // vor branch: concat([vor_l, vor_r]) @ W.T; bias added only by left half
        float mask = (dmax == 1 || dmax == 4) ? 1.0f : 0.0f;
        int off = half * 64;
        float a0 = (half == 0) ? vor_fc_b[0] : 0.0f;
        float a1 = (half == 0) ? vor_fc_b[1] : 0.0f;
#pragma unroll
        for (int k = 0; k < HDIM; ++k) {
            a0 += vor_fc_W[off + k] * h1[k]       + vor_fc_W[off + HDIM + k] * h1b[k];
            a1 += vor_fc_W[128 + off + k] * h1[k] + vor_fc_W[128 + off + HDIM + k] * h1b[k];
        }
        o0 = a0 * mask;
        o1 = a1 * mask;
    }

    atomicAdd(out + (size_t)b * 2 + 0, o0);
    atomicAdd(out + (size_t)b * 2 + 1, o1);
}

extern "C" void kernel_launch(void* const* d_in, const int* in_sizes, int n_in,
                              void* d_out, int out_size, void* d_ws, size_t ws_size,
                              hipStream_t stream) {
    const float* dir_input = (const float*)d_in[0];
    const float* pos       = (const float*)d_in[1];
    const float* lvl_Wih0  = (const float*)d_in[2];
    const float* lvl_Whh0  = (const float*)d_in[3];
    const float* lvl_b0    = (const float*)d_in[4];
    const float* lvl_Wih1  = (const float*)d_in[5];
    const float* lvl_Whh1  = (const float*)d_in[6];
    const float* lvl_b1    = (const float*)d_in[7];
    const float* vor_Wih0  = (const float*)d_in[8];
    const float* vor_Whh0  = (const float*)d_in[9];
    const float* vor_b0    = (const float*)d_in[10];
    const float* vor_Wih1  = (const float*)d_in[11];
    const float* vor_Whh1  = (const float*)d_in[12];
    const float* vor_b1    = (const float*)d_in[13];
    const float* lvl_fc_W  = (const float*)d_in[14];
    const float* lvl_fc_b  = (const float*)d_in[15];
    const float* vor_fc_W  = (const float*)d_in[16];
    const float* vor_fc_b  = (const float*)d_in[17];
    float* out = (float*)d_out;

    (void)in_sizes; (void)n_in; (void)d_ws; (void)ws_size;

    hipMemsetAsync(d_out, 0, (size_t)out_size * sizeof(float), stream);

    dim3 grid(256, 2, 1);   // 65536 samples / 256 threads, y = model (lvl/vor)
    dim3 block(256, 1, 1);
    hipLaunchKernelGGL(lstm_fused, grid, block, 0, stream,
                       dir_input, pos,
                       lvl_Wih0, lvl_Whh0, lvl_b0, lvl_Wih1, lvl_Whh1, lvl_b1,
                       vor_Wih0, vor_Whh0, vor_b0, vor_Wih1, vor_Whh1, vor_b1,
                       lvl_fc_W, lvl_fc_b, vor_fc_W, vor_fc_b,
                       out);
}